// Round 2
// baseline (2221.134 us; speedup 1.0000x reference)
//
#include <hip/hip_runtime.h>
#include <hip/hip_bf16.h>
#include <stdint.h>
#include <stddef.h>

#define B_  32
#define S_  400
#define T_  32
#define H_  512
#define E_  128
#define V_  50000
#define A_  512
#define H2_ 1024
#define H3_ 1536
#define H4_ 2048
#define R_  1024     // B*T
#define PGK_ 1664    // 3H+E

typedef unsigned short u16;
typedef short v8s __attribute__((ext_vector_type(8)));
typedef float v4f __attribute__((ext_vector_type(4)));

__device__ __forceinline__ float fsig(float x){ return 1.0f/(1.0f + __expf(-x)); }
__device__ __forceinline__ float ftanh(float x){ float e = __expf(2.0f*x); return 1.0f - 2.0f/(e + 1.0f); }
__device__ __forceinline__ u16 f2bf(float x){ __hip_bfloat16 b = __float2bfloat16(x); return *reinterpret_cast<u16*>(&b); }
__device__ __forceinline__ float bf2f(u16 u){ __hip_bfloat16 b = *reinterpret_cast<__hip_bfloat16*>(&u); return __bfloat162float(b); }

__device__ __forceinline__ float wsum(float v){
  #pragma unroll
  for (int off = 32; off > 0; off >>= 1) v += __shfl_xor(v, off, 64);
  return v;
}
__device__ __forceinline__ float wmax(float v){
  #pragma unroll
  for (int off = 32; off > 0; off >>= 1) v = fmaxf(v, __shfl_xor(v, off, 64));
  return v;
}

// ---------------- setup kernels ----------------

__global__ void k_init(const float* __restrict__ h0, const float* __restrict__ c0,
                       float* __restrict__ h_ws, float* __restrict__ c_ws, float* __restrict__ cov_ws){
  int i = blockIdx.x*256 + threadIdx.x;
  if (i < B_*H_){ h_ws[i] = h0[i]; c_ws[i] = c0[i]; }
  if (i < B_*S_){ cov_ws[i] = 0.0f; }
}

__global__ __launch_bounds__(256) void k_transpose(const float* __restrict__ in, float* __restrict__ out, int R, int C){
  __shared__ float tile[64][65];
  int c0 = blockIdx.x*64, r0 = blockIdx.y*64;
  int tid = threadIdx.x;
  int cl = tid & 63, q = tid >> 6;
  #pragma unroll
  for (int i=0;i<16;i++){
    int r = q + i*4;
    float v = 0.0f;
    if (r0 + r < R && c0 + cl < C) v = in[(size_t)(r0+r)*C + c0 + cl];
    tile[r][cl] = v;
  }
  __syncthreads();
  #pragma unroll
  for (int i=0;i<16;i++){
    int c = q + i*4;
    if (c0 + c < C && r0 + cl < R)
      out[(size_t)(c0+c)*R + r0 + cl] = tile[cl][c];
  }
}

// f32 [R][C] -> bf16 [C][R] (hi) and optional residual (lo) for split-bf16
__global__ __launch_bounds__(256) void k_convT(const float* __restrict__ in, u16* __restrict__ hi, u16* __restrict__ lo, int R, int C){
  __shared__ float tile[64][65];
  int c0 = blockIdx.x*64, r0 = blockIdx.y*64;
  int tid = threadIdx.x;
  int cl = tid & 63, q = tid >> 6;
  #pragma unroll
  for (int i=0;i<16;i++){
    int r = q + i*4;
    float v = 0.0f;
    if (r0 + r < R && c0 + cl < C) v = in[(size_t)(r0+r)*C + c0 + cl];
    tile[r][cl] = v;
  }
  __syncthreads();
  #pragma unroll
  for (int i=0;i<16;i++){
    int c = q + i*4;
    if (c0 + c < C && r0 + cl < R){
      float v = tile[cl][c];
      u16 h = f2bf(v);
      size_t o = (size_t)(c0+c)*R + r0 + cl;
      hi[o] = h;
      if (lo) lo[o] = f2bf(v - bf2f(h));
    }
  }
}

__global__ void k_conv_hilo(const float* __restrict__ in, u16* __restrict__ hi, u16* __restrict__ lo, int n4){
  int i = blockIdx.x*256 + threadIdx.x;
  if (i >= n4) return;
  float4 x = reinterpret_cast<const float4*>(in)[i];
  u16 a0 = f2bf(x.x), a1 = f2bf(x.y), a2 = f2bf(x.z), a3 = f2bf(x.w);
  uint2 hv; hv.x = (unsigned)a0 | ((unsigned)a1 << 16); hv.y = (unsigned)a2 | ((unsigned)a3 << 16);
  reinterpret_cast<uint2*>(hi)[i] = hv;
  u16 l0 = f2bf(x.x - bf2f(a0)), l1 = f2bf(x.y - bf2f(a1));
  u16 l2 = f2bf(x.z - bf2f(a2)), l3 = f2bf(x.w - bf2f(a3));
  uint2 lv; lv.x = (unsigned)l0 | ((unsigned)l1 << 16); lv.y = (unsigned)l2 | ((unsigned)l3 << 16);
  reinterpret_cast<uint2*>(lo)[i] = lv;
}

// G_ih[r][j] = b_ih[j]+b_hh[j] + sum_e emb[r][e]*W_ih[j][e]  (uses WihT[e][j])
__global__ __launch_bounds__(256) void k_gih(const float* __restrict__ emb, const float* __restrict__ WihT,
    const float* __restrict__ b_ih, const float* __restrict__ b_hh, float* __restrict__ G){
  __shared__ float em[8][128];
  int r0 = blockIdx.x*8;
  int tid = threadIdx.x;
  #pragma unroll
  for (int i=0;i<4;i++){
    int e = i*256 + tid;
    em[e>>7][e&127] = emb[(size_t)(r0 + (e>>7))*E_ + (e&127)];
  }
  __syncthreads();
  for (int jj=0;jj<8;jj++){
    int j = jj*256 + tid;
    float bias = b_ih[j] + b_hh[j];
    float acc[8];
    #pragma unroll
    for (int r=0;r<8;r++) acc[r] = bias;
    for (int e=0;e<128;e++){
      float wv = WihT[(size_t)e*H4_ + j];
      #pragma unroll
      for (int r=0;r<8;r++) acc[r] += em[r][e]*wv;
    }
    #pragma unroll
    for (int r=0;r<8;r++) G[(size_t)(r0+r)*H4_ + j] = acc[r];
  }
}

// ---------------- MFMA bf16 GEMM: C[M][N] (+= / =) A[M][K] * Bt[N][K]^T (+bias) ----------------
__global__ __launch_bounds__(256, 2) void k_gemm_bf16(
    const u16* __restrict__ A, int lda, const u16* __restrict__ Bt, int ldb,
    const float* __restrict__ bias, float* __restrict__ C, int ldc,
    int M, int N, int K, int accum)
{
  __shared__ __align__(16) u16 As[128*64];
  __shared__ __align__(16) u16 Bs[128*64];
  const int tid = threadIdx.x;
  const int m0 = blockIdx.y * 128;
  const int n0 = blockIdx.x * 128;
  const int l  = tid & 63;
  const int wavebase = tid & ~63;
  const int wid = tid >> 6;
  const int wm = (wid >> 1) * 64;
  const int wn = (wid & 1) * 64;

  v4f acc[4][4];
  v4f vzero = {0.0f, 0.0f, 0.0f, 0.0f};
  #pragma unroll
  for (int i=0;i<4;i++)
    #pragma unroll
    for (int j=0;j<4;j++) acc[i][j] = vzero;

  for (int k0 = 0; k0 < K; k0 += 64){
    __syncthreads();
    #pragma unroll
    for (int jj=0;jj<4;jj++){
      int fc = jj*256 + tid;          // flat 16B-chunk id: 128 rows x 8 chunks
      int row = fc >> 3;
      int cc = (fc & 7) ^ (row & 7);  // inverse-swizzled source chunk
      const u16* g = A + (size_t)(m0 + row)*lda + k0 + cc*8;
      __builtin_amdgcn_global_load_lds(
        (__attribute__((address_space(1))) void*)g,
        (__attribute__((address_space(3))) void*)(As + (size_t)(jj*256 + wavebase)*8),
        16, 0, 0);
    }
    #pragma unroll
    for (int jj=0;jj<4;jj++){
      int fc = jj*256 + tid;
      int row = fc >> 3;
      int cc = (fc & 7) ^ (row & 7);
      int rn = n0 + row; if (rn > N-1) rn = N-1;   // clamp for N-tail (stores guarded)
      const u16* g = Bt + (size_t)rn*ldb + k0 + cc*8;
      __builtin_amdgcn_global_load_lds(
        (__attribute__((address_space(1))) void*)g,
        (__attribute__((address_space(3))) void*)(Bs + (size_t)(jj*256 + wavebase)*8),
        16, 0, 0);
    }
    __syncthreads();
    #pragma unroll
    for (int ks=0;ks<2;ks++){
      v8s af[4], bfr[4];
      #pragma unroll
      for (int rt=0;rt<4;rt++){
        int r = wm + rt*16 + (l & 15);
        int cs = (ks*4 + (l >> 4)) ^ (r & 7);
        af[rt] = *reinterpret_cast<const v8s*>(As + r*64 + cs*8);
      }
      #pragma unroll
      for (int nt=0;nt<4;nt++){
        int r = wn + nt*16 + (l & 15);
        int cs = (ks*4 + (l >> 4)) ^ (r & 7);
        bfr[nt] = *reinterpret_cast<const v8s*>(Bs + r*64 + cs*8);
      }
      #pragma unroll
      for (int rt=0;rt<4;rt++)
        #pragma unroll
        for (int nt=0;nt<4;nt++)
          acc[rt][nt] = __builtin_amdgcn_mfma_f32_16x16x32_bf16(af[rt], bfr[nt], acc[rt][nt], 0, 0, 0);
    }
  }

  const int cl = l & 15;
  const int rg = (l >> 4) * 4;
  #pragma unroll
  for (int rt=0;rt<4;rt++){
    int gr = m0 + wm + rt*16 + rg;
    #pragma unroll
    for (int nt=0;nt<4;nt++){
      int gc = n0 + wn + nt*16 + cl;
      if (gc < N){
        float* cp = C + (size_t)gr*ldc + gc;
        if (accum){
          #pragma unroll
          for (int i=0;i<4;i++) cp[(size_t)i*ldc] += acc[rt][nt][i];
        } else {
          float bv = bias ? bias[gc] : 0.0f;
          #pragma unroll
          for (int i=0;i<4;i++) cp[(size_t)i*ldc] = acc[rt][nt][i] + bv;
        }
      }
    }
  }
}

// fallback f32 GEMM for W_v when ws too small: logits = dec_states @ W_v + b_v
__global__ __launch_bounds__(256) void k_wv_f32(
  const float* __restrict__ Aah, const float* __restrict__ Wv, const float* __restrict__ bv,
  float* __restrict__ Cl)
{
  __shared__ float Asf[32][68];
  __shared__ float Bsf[32][64];
  int n0 = blockIdx.x*64, m0 = blockIdx.y*64;
  int tid = threadIdx.x;
  int tx = tid & 15, ty = tid >> 4;
  float acc[4][4] = {};
  for (int kc = 0; kc < H_; kc += 32){
    __syncthreads();
    #pragma unroll
    for (int i=0;i<8;i++){
      int e = i*256 + tid;
      Asf[e & 31][e >> 5] = Aah[(size_t)(m0 + (e >> 5))*H_ + kc + (e & 31)];
    }
    #pragma unroll
    for (int i=0;i<8;i++){
      int e = i*256 + tid;
      int nc = n0 + (e & 63); if (nc >= V_) nc = V_-1;
      Bsf[e >> 6][e & 63] = Wv[(size_t)(kc + (e >> 6))*V_ + nc];
    }
    __syncthreads();
    #pragma unroll
    for (int k=0;k<32;k++){
      float4 a4 = *reinterpret_cast<const float4*>(&Asf[k][ty*4]);
      float4 b4 = *reinterpret_cast<const float4*>(&Bsf[k][tx*4]);
      float av[4] = {a4.x, a4.y, a4.z, a4.w};
      float bv4[4] = {b4.x, b4.y, b4.z, b4.w};
      #pragma unroll
      for (int i=0;i<4;i++)
        #pragma unroll
        for (int j=0;j<4;j++)
          acc[i][j] = __builtin_fmaf(av[i], bv4[j], acc[i][j]);
    }
  }
  #pragma unroll
  for (int i=0;i<4;i++){
    int rr = m0 + ty*4 + i;
    #pragma unroll
    for (int j=0;j<4;j++){
      int cc = n0 + tx*4 + j;
      if (cc < V_) Cl[(size_t)rr*V_ + cc] = acc[i][j] + bv[cc];
    }
  }
}

// ---------------- per-step kernels ----------------

// split-K partial of gates: gp[ks][b][j] = sum_{k in ks-range} h[b][k]*W_hh[j][k]
__global__ __launch_bounds__(256) void k_gates(const float* __restrict__ h_ws, const float* __restrict__ WhhT, float* __restrict__ gp){
  __shared__ float hs[64][36];
  __shared__ float red[128][33];
  int ks = blockIdx.x;          // 0..7 (k-range 64)
  int j0 = blockIdx.y * 128;    // 0..15
  int k0 = ks * 64;
  int tid = threadIdx.x;
  #pragma unroll
  for (int i=0;i<8;i++){
    int e = i*256 + tid;
    int b = e >> 6, kl = e & 63;
    hs[kl][b] = h_ws[b*H_ + k0 + kl];
  }
  __syncthreads();
  int jl = tid & 127, kh = tid >> 7;
  int j = j0 + jl;
  float acc[32];
  #pragma unroll
  for (int b=0;b<32;b++) acc[b] = 0.0f;
  #pragma unroll 4
  for (int kk=0;kk<32;kk++){
    int k = kh*32 + kk;
    float wv = WhhT[(size_t)(k0 + k)*H4_ + j];
    #pragma unroll
    for (int bb=0;bb<8;bb++){
      float4 hv = *reinterpret_cast<const float4*>(&hs[k][bb*4]);
      acc[bb*4+0] += hv.x*wv;
      acc[bb*4+1] += hv.y*wv;
      acc[bb*4+2] += hv.z*wv;
      acc[bb*4+3] += hv.w*wv;
    }
  }
  if (kh){
    #pragma unroll
    for (int b=0;b<32;b++) red[jl][b] = acc[b];
  }
  __syncthreads();
  if (!kh){
    #pragma unroll
    for (int b=0;b<32;b++)
      gp[(size_t)(ks*32 + b)*H4_ + j] = acc[b] + red[jl][b];
  }
}

// finish LSTM pointwise (redundantly per aq) + dec partial over this block's k-range
__global__ __launch_bounds__(256) void k_dech(
  const float* __restrict__ gp, const float* __restrict__ G,
  const float* __restrict__ c_r, float* __restrict__ c_w,
  float* __restrict__ h_ws, float* __restrict__ h_all,
  const float* __restrict__ W_dec, float* __restrict__ decp, int t)
{
  __shared__ float hs[128][12];
  __shared__ float red[128][9];
  int aq = blockIdx.x, ks = blockIdx.y, bg = blockIdx.z;  // 4,4,4
  int tid = threadIdx.x;
  #pragma unroll
  for (int i=0;i<4;i++){
    int e = i*256 + tid;
    int bl = e >> 7, kl = e & 127;
    int b = bg*8 + bl;
    int hidx = ks*128 + kl;
    int r = b*T_ + t;
    const float* Gr = G + (size_t)r*H4_ + hidx;
    float gi = Gr[0], gf = Gr[512], gg = Gr[1024], go = Gr[1536];
    #pragma unroll
    for (int p=0;p<8;p++){
      const float* gpb = gp + (size_t)(p*32 + b)*H4_ + hidx;
      gi += gpb[0]; gf += gpb[512]; gg += gpb[1024]; go += gpb[1536];
    }
    float co = c_r[b*H_ + hidx];
    float cn = fsig(gf)*co + fsig(gi)*ftanh(gg);
    float hn = fsig(go)*ftanh(cn);
    hs[kl][bl] = hn;
    if (aq == 0){
      c_w[b*H_ + hidx] = cn;
      h_ws[b*H_ + hidx] = hn;
      h_all[(size_t)r*H_ + hidx] = hn;
    }
  }
  __syncthreads();
  int al = tid & 127, kh = tid >> 7;
  int a = aq*128 + al;
  float acc[8];
  #pragma unroll
  for (int i=0;i<8;i++) acc[i] = 0.0f;
  #pragma unroll 4
  for (int kk=0;kk<64;kk++){
    int k = kh*64 + kk;
    float wv = W_dec[(size_t)(ks*128 + k)*A_ + a];
    float4 hv0 = *reinterpret_cast<const float4*>(&hs[k][0]);
    float4 hv1 = *reinterpret_cast<const float4*>(&hs[k][4]);
    acc[0] += hv0.x*wv; acc[1] += hv0.y*wv; acc[2] += hv0.z*wv; acc[3] += hv0.w*wv;
    acc[4] += hv1.x*wv; acc[5] += hv1.y*wv; acc[6] += hv1.z*wv; acc[7] += hv1.w*wv;
  }
  if (kh){
    #pragma unroll
    for (int i=0;i<8;i++) red[al][i] = acc[i];
  }
  __syncthreads();
  if (!kh){
    #pragma unroll
    for (int bl=0;bl<8;bl++)
      decp[(size_t)(ks*32 + bg*8 + bl)*A_ + a] = acc[bl] + red[al][bl];
  }
}

// scores[b][s] = v . tanh(ep[b,s,:] + dec[b,:] + cov[b,s]*w_cov)   (b_att folded into ep)
__global__ __launch_bounds__(256) void k_scores(
  const float* __restrict__ ep, const float* __restrict__ decp,
  const float* __restrict__ w_cov, const float* __restrict__ v_att,
  const float* __restrict__ cov_ws, const void* __restrict__ maskp,
  float* __restrict__ sc_ws)
{
  __shared__ float decs[512], wc[512], va[512];
  int sq = blockIdx.x, b = blockIdx.y;
  int tid = threadIdx.x;
  #pragma unroll
  for (int i=0;i<2;i++){
    int a = i*256 + tid;
    float d = 0.0f;
    #pragma unroll
    for (int p=0;p<4;p++) d += decp[(size_t)(p*32 + b)*A_ + a];
    decs[a] = d;
    wc[a] = w_cov[a];
    va[a] = v_att[a];
  }
  __syncthreads();
  // mask dtype detection: byte-bool vs 4-byte (int32/float32) elements
  const unsigned* m32 = (const unsigned*)maskp;
  const unsigned char* m8 = (const unsigned char*)maskp;
  bool bytemode = (m32[0] == 0x01010101u);
  int w = tid >> 6, l = tid & 63;
  for (int si=0; si<13; si++){
    int sl = w + si*4;
    if (sl >= 50) break;
    int s = sq*50 + sl;
    float cv = cov_ws[b*S_ + s];
    const float* epr = ep + (size_t)(b*S_ + s)*A_;
    float part = 0.0f;
    #pragma unroll
    for (int i=0;i<8;i++){
      int a = l + i*64;
      float x = epr[a] + decs[a] + cv*wc[a];
      part += va[a]*ftanh(x);
    }
    part = wsum(part);
    if (l == 0){
      bool on = bytemode ? (m8[b*S_ + s] != 0) : (m32[b*S_ + s] != 0u);
      sc_ws[b*S_ + s] = on ? part : -1e9f;
    }
  }
}

// softmax (recomputed per block) + attn/cov outputs (dq==0) + context partial
__global__ __launch_bounds__(256) void k_context(
  const float* __restrict__ sc_ws, float* __restrict__ cov_ws,
  const float* __restrict__ enc, float* __restrict__ ctxp,
  float* __restrict__ attns_out, float* __restrict__ covs_out, int t)
{
  __shared__ float att[100];
  __shared__ float cw[8];
  int dq = blockIdx.x, sh = blockIdx.y, b = blockIdx.z;
  int tid = threadIdx.x;
  int w = tid >> 6;
  float v1 = sc_ws[b*S_ + tid];
  float v2 = (tid + 256 < S_) ? sc_ws[b*S_ + tid + 256] : -1e30f;
  float mx = wmax(fmaxf(v1, v2));
  if ((tid & 63) == 0) cw[w] = mx;
  __syncthreads();
  float m4 = fmaxf(fmaxf(cw[0], cw[1]), fmaxf(cw[2], cw[3]));
  float e1 = __expf(v1 - m4) + ((tid + 256 < S_) ? __expf(v2 - m4) : 0.0f);
  float sm = wsum(e1);
  if ((tid & 63) == 0) cw[4 + w] = sm;
  __syncthreads();
  float invZ = 1.0f/(cw[4] + cw[5] + cw[6] + cw[7]);
  int r = b*T_ + t;
  if (tid < 100){
    int s = sh*100 + tid;
    float aval = __expf(sc_ws[b*S_ + s] - m4)*invZ;
    att[tid] = aval;
    if (dq == 0){
      attns_out[(size_t)r*S_ + s] = aval;
      float cn = cov_ws[b*S_ + s] + aval;
      covs_out[(size_t)r*S_ + s] = cn;
      cov_ws[b*S_ + s] = cn;
    }
  }
  __syncthreads();
  int d = dq*256 + tid;
  const float* encb = enc + (size_t)(b*S_ + sh*100)*H2_ + d;
  float accv = 0.0f;
  #pragma unroll 4
  for (int si=0; si<100; si++)
    accv += att[si]*encb[(size_t)si*H2_];
  ctxp[(size_t)(sh*R_ + r)*H2_ + d] = accv;
}

// ---------------- post-loop kernels ----------------

__global__ void k_catsum(const float* __restrict__ ctxp, const float* __restrict__ h_all, float* __restrict__ catbuf){
  int r = blockIdx.y;
  int d = blockIdx.x*256 + threadIdx.x;
  float v;
  if (d < H2_){
    v = ctxp[(size_t)(0*R_ + r)*H2_ + d] + ctxp[(size_t)(1*R_ + r)*H2_ + d]
      + ctxp[(size_t)(2*R_ + r)*H2_ + d] + ctxp[(size_t)(3*R_ + r)*H2_ + d];
  } else {
    v = h_all[(size_t)r*H_ + (d - H2_)];
  }
  catbuf[(size_t)r*H3_ + d] = v;
}

// fp32 tiled GEMM: dec_states = tanh(catbuf @ W_ah + b_ah); optional bf16 copy
__global__ __launch_bounds__(256) void k_ahgemm(
  const float* __restrict__ Acat, const float* __restrict__ W_ah, const float* __restrict__ b_ah,
  float* __restrict__ dec_states, u16* __restrict__ ah_bf)
{
  __shared__ float Asf[32][68];
  __shared__ float Bsf[32][64];
  int n0 = blockIdx.x*64, m0 = blockIdx.y*64;
  int tid = threadIdx.x;
  int tx = tid & 15, ty = tid >> 4;
  float acc[4][4] = {};
  for (int kc = 0; kc < H3_; kc += 32){
    __syncthreads();
    #pragma unroll
    for (int i=0;i<8;i++){
      int e = i*256 + tid;
      Asf[e & 31][e >> 5] = Acat[(size_t)(m0 + (e >> 5))*H3_ + kc + (e & 31)];
    }
    #pragma unroll
    for (int i=0;i<8;i++){
      int e = i*256 + tid;
      Bsf[e >> 6][e & 63] = W_ah[(size_t)(kc + (e >> 6))*H_ + n0 + (e & 63)];
    }
    __syncthreads();
    #pragma unroll
    for (int k=0;k<32;k++){
      float4 a4 = *reinterpret_cast<const float4*>(&Asf[k][ty*4]);
      float4 b4 = *reinterpret_cast<const float4*>(&Bsf[k][tx*4]);
      float av[4] = {a4.x, a4.y, a4.z, a4.w};
      float bv[4] = {b4.x, b4.y, b4.z, b4.w};
      #pragma unroll
      for (int i=0;i<4;i++)
        #pragma unroll
        for (int j=0;j<4;j++)
          acc[i][j] = __builtin_fmaf(av[i], bv[j], acc[i][j]);
    }
  }
  #pragma unroll
  for (int i=0;i<4;i++){
    int rr = m0 + ty*4 + i;
    #pragma unroll
    for (int j=0;j<4;j++){
      int cc = n0 + tx*4 + j;
      float v = ftanh(acc[i][j] + b_ah[cc]);
      dec_states[(size_t)rr*H_ + cc] = v;
      if (ah_bf) ah_bf[(size_t)rr*H_ + cc] = f2bf(v);
    }
  }
}

__global__ __launch_bounds__(512) void k_pgen(const float* __restrict__ catbuf, const float* __restrict__ emb,
  const float* __restrict__ W_pg, const float* __restrict__ b_pg, float* __restrict__ pgens)
{
  int w = threadIdx.x >> 6, l = threadIdx.x & 63;
  int r = blockIdx.x*8 + w;
  float part = 0.0f;
  for (int d = l; d < PGK_; d += 64){
    float x = (d < H3_) ? catbuf[(size_t)r*H3_ + d] : emb[(size_t)r*E_ + (d - H3_)];
    part += x*W_pg[d];
  }
  part = wsum(part);
  if (l == 0) pgens[r] = fsig(part + b_pg[0]);
}

// per-row: online max/Z -> LDS token-hash of scatter adds -> single transform+log pass (in place)
__global__ __launch_bounds__(512) void k_final(
  float* __restrict__ logits, const float* __restrict__ pgens,
  const float* __restrict__ attns, const int* __restrict__ src)
{
  __shared__ unsigned int keys[1024];
  __shared__ float vals[1024];
  __shared__ float sred[16];
  int r = blockIdx.x;
  int b = r >> 5;
  int tid = threadIdx.x;
  float* row = logits + (size_t)r*V_;
  float m = -1e30f, Z = 0.0f;
  for (int v = tid; v < V_; v += 512){
    float x = row[v];
    float nm = fmaxf(m, x);
    Z = Z*__expf(m - nm) + __expf(x - nm);
    m = nm;
  }
  #pragma unroll
  for (int off=32; off>0; off>>=1){
    float mo = __shfl_xor(m, off, 64);
    float Zo = __shfl_xor(Z, off, 64);
    float nm = fmaxf(m, mo);
    Z = Z*__expf(m - nm) + Zo*__expf(mo - nm);
    m = nm;
  }
  int w = tid >> 6, l = tid & 63;
  if (l == 0){ sred[w*2] = m; sred[w*2+1] = Z; }
  for (int i = tid; i < 1024; i += 512){ keys[i] = 0xFFFFFFFFu; vals[i] = 0.0f; }
  __syncthreads();
  if (tid == 0){
    float gm = -1e30f, gz = 0.0f;
    #pragma unroll
    for (int i=0;i<8;i++){
      float mi = sred[i*2], zi = sred[i*2+1];
      float nm = fmaxf(gm, mi);
      gz = gz*__expf(gm - nm) + zi*__expf(mi - nm);
      gm = nm;
    }
    sred[0] = gm; sred[1] = gz;
  }
  __syncthreads();
  float gm = sred[0];
  float pg = pgens[r];
  float scale = pg / sred[1];
  if (tid < S_){
    int tok = src[b*S_ + tid];
    float add = (1.0f - pg)*attns[(size_t)r*S_ + tid];
    unsigned int h = ((unsigned int)tok * 2654435761u) >> 22;
    while (true){
      unsigned int prev = atomicCAS(&keys[h], 0xFFFFFFFFu, (unsigned int)tok);
      if (prev == 0xFFFFFFFFu || prev == (unsigned int)tok){
        atomicAdd(&vals[h], add);
        break;
      }
      h = (h + 1) & 1023;
    }
  }
  __syncthreads();
  for (int v = tid; v < V_; v += 512){
    float x = row[v];
    float p = __expf(x - gm)*scale;
    unsigned int h = ((unsigned int)v * 2654435761u) >> 22;
    while (keys[h] != 0xFFFFFFFFu){
      if (keys[h] == (unsigned int)v){ p += vals[h]; break; }
      h = (h + 1) & 1023;
    }
    row[v] = __logf(p + 1e-20f);
  }
}

// ---------------- host ----------------

extern "C" void kernel_launch(void* const* d_in, const int* in_sizes, int n_in,
                              void* d_out, int out_size, void* d_ws, size_t ws_size,
                              hipStream_t stream)
{
  const int* src_tokens = (const int*)d_in[0];
  const float* embedded = (const float*)d_in[1];
  const float* enc      = (const float*)d_in[2];
  const void*  maskp    = (const void*)d_in[3];
  const float* h0  = (const float*)d_in[4];
  const float* c0  = (const float*)d_in[5];
  const float* W_ih = (const float*)d_in[6];
  const float* W_hh = (const float*)d_in[7];
  const float* b_ih = (const float*)d_in[8];
  const float* b_hh = (const float*)d_in[9];
  const float* W_enc = (const float*)d_in[10];
  const float* W_dec = (const float*)d_in[11];
  const float* w_cov = (const float*)d_in[12];
  const float* b_att = (const float*)d_in[13];
  const float* v_att = (const float*)d_in[14];
  const float* W_ah  = (const float*)d_in[15];
  const float* b_ah  = (const float*)d_in[16];
  const float* W_pg  = (const float*)d_in[17];
  const float* b_pg  = (const float*)d_in[18];
  const float* W_v   = (const float*)d_in[19];
  const float* b_v   = (const float*)d_in[20];
  (void)in_sizes; (void)n_in; (void)out_size;

  float* outp = (float*)d_out;
  float* logps = outp;                                  // (B,T,V)   204.8 MB
  float* dec_states = logps + (size_t)R_*V_;            // (B,T,H)
  float* attns = dec_states + (size_t)R_*H_;            // (B,T,S)
  float* covs  = attns + (size_t)R_*S_;                 // (B,T,S)
  float* pgens = covs + (size_t)R_*S_;                  // (B,T)

  // ---- big transients live INSIDE the logps output region (dead until W_v GEMM) ----
  char* sp = (char*)logps;
  auto salloc = [&](size_t bytes) -> void* {
    void* p = (void*)sp;
    sp += (bytes + 255) & ~(size_t)255;
    return p;
  };
  float* ep     = (float*)salloc((size_t)B_*S_*A_*4);    // enc_proj + b_att
  u16* enc_hi   = (u16*)salloc((size_t)B_*S_*H2_*2);
  u16* enc_lo   = (u16*)salloc((size_t)B_*S_*H2_*2);
  u16* WencT_hi = (u16*)salloc((size_t)A_*H2_*2);
  u16* WencT_lo = (u16*)salloc((size_t)A_*H2_*2);
  float* WihT   = (float*)salloc((size_t)E_*H4_*4);
  float* WhhT   = (float*)salloc((size_t)H_*H4_*4);
  float* Gih    = (float*)salloc((size_t)R_*H4_*4);      // emb@W_ih^T + biases
  float* ctxp   = (float*)salloc((size_t)4*R_*H2_*4);    // context s-partials
  float* catbuf = (float*)salloc((size_t)R_*H3_*4);      // [context | h]
  float* h_all  = (float*)salloc((size_t)R_*H_*4);
  float* gp     = (float*)salloc((size_t)8*B_*H4_*4);    // gate k-partials
  float* decp   = (float*)salloc((size_t)4*B_*A_*4);     // dec k-partials
  float* sc_ws  = (float*)salloc((size_t)B_*S_*4);
  float* cov_ws = (float*)salloc((size_t)B_*S_*4);
  float* h_ws   = (float*)salloc((size_t)B_*H_*4);
  float* c_ws0  = (float*)salloc((size_t)B_*H_*4);
  float* c_ws1  = (float*)salloc((size_t)B_*H_*4);
  // total ~122.2 MB < 204.8 MB of logps  -- all consumed before W_v GEMM writes logps

  // ---- d_ws: only buffers live WHILE logps is being written ----
  char* wp = (char*)d_ws;
  auto walloc = [&](size_t bytes) -> void* {
    void* p = (void*)wp;
    wp += (bytes + 255) & ~(size_t)255;
    return p;
  };
  u16* ah_bf = (u16*)walloc((size_t)R_*H_*2);            // 1.05 MB
  u16* WvT   = (u16*)walloc((size_t)V_*H_*2);            // 51.2 MB
  const size_t ws_needed = (size_t)R_*H_*2 + (size_t)V_*H_*2 + 512;
  const bool fast_wv = (ws_size >= ws_needed);

  // setup
  k_init<<<64, 256, 0, stream>>>(h0, c0, h_ws, c_ws0, cov_ws);
  k_transpose<<<dim3(8,32), 256, 0, stream>>>(W_hh, WhhT, H4_, H_);
  k_transpose<<<dim3(2,32), 256, 0, stream>>>(W_ih, WihT, H4_, E_);
  k_gih<<<128, 256, 0, stream>>>(embedded, WihT, b_ih, b_hh, Gih);
  k_conv_hilo<<<(B_*S_*H2_/4 + 255)/256, 256, 0, stream>>>(enc, enc_hi, enc_lo, B_*S_*H2_/4);
  k_convT<<<dim3(8,16), 256, 0, stream>>>(W_enc, WencT_hi, WencT_lo, H2_, A_);
  if (fast_wv)
    k_convT<<<dim3((V_+63)/64, 8), 256, 0, stream>>>(W_v, WvT, (u16*)nullptr, H_, V_);

  // enc_proj (split-bf16, 3 passes: Ah*Bh + Ah*Bl + Al*Bh), bias=b_att on pass 1
  dim3 gep(A_/128, (B_*S_)/128);
  k_gemm_bf16<<<gep, 256, 0, stream>>>(enc_hi, H2_, WencT_hi, H2_, b_att, ep, A_, B_*S_, A_, H2_, 0);
  k_gemm_bf16<<<gep, 256, 0, stream>>>(enc_hi, H2_, WencT_lo, H2_, nullptr, ep, A_, B_*S_, A_, H2_, 1);
  k_gemm_bf16<<<gep, 256, 0, stream>>>(enc_lo, H2_, WencT_hi, H2_, nullptr, ep, A_, B_*S_, A_, H2_, 1);

  // recurrence
  for (int t = 0; t < T_; ++t){
    float* c_r = (t & 1) ? c_ws1 : c_ws0;
    float* c_w = (t & 1) ? c_ws0 : c_ws1;
    k_gates<<<dim3(8,16), 256, 0, stream>>>(h_ws, WhhT, gp);
    k_dech<<<dim3(4,4,4), 256, 0, stream>>>(gp, Gih, c_r, c_w, h_ws, h_all, W_dec, decp, t);
    k_scores<<<dim3(8,32), 256, 0, stream>>>(ep, decp, w_cov, v_att, cov_ws, maskp, sc_ws);
    k_context<<<dim3(4,4,32), 256, 0, stream>>>(sc_ws, cov_ws, enc, ctxp, attns, covs, t);
  }

  // batched tail
  k_catsum<<<dim3(6, R_), 256, 0, stream>>>(ctxp, h_all, catbuf);
  k_ahgemm<<<dim3(8,16), 256, 0, stream>>>(catbuf, W_ah, b_ah, dec_states, fast_wv ? ah_bf : (u16*)nullptr);
  k_pgen<<<128, 512, 0, stream>>>(catbuf, embedded, W_pg, b_pg, pgens);

  // logits: overwrites the whole logps region (including all scratch above)
  if (fast_wv)
    k_gemm_bf16<<<dim3((V_+127)/128, R_/128), 256, 0, stream>>>(ah_bf, H_, WvT, H_, b_v, logps, V_, R_, V_, H_, 0);
  else
    k_wv_f32<<<dim3((V_+63)/64, R_/64), 256, 0, stream>>>(dec_states, W_v, b_v, logps);

  k_final<<<R_, 512, 0, stream>>>(logps, pgens, attns, src_tokens);
}

// Round 3
// 2010.864 us; speedup vs baseline: 1.1046x; 1.1046x over previous
//
#include <hip/hip_runtime.h>
#include <hip/hip_bf16.h>
#include <stdint.h>
#include <stddef.h>

#define B_  32
#define S_  400
#define T_  32
#define H_  512
#define E_  128
#define V_  50000
#define A_  512
#define H2_ 1024
#define H3_ 1536
#define H4_ 2048
#define R_  1024     // B*T
#define PGK_ 1664    // 3H+E
#define NBLKV_ 391   // ceil(V/128)

typedef unsigned short u16;
typedef short v8s __attribute__((ext_vector_type(8)));
typedef float v4f __attribute__((ext_vector_type(4)));

__device__ __forceinline__ float fsig(float x){ return 1.0f/(1.0f + __expf(-x)); }
__device__ __forceinline__ float ftanh(float x){ float e = __expf(2.0f*x); return 1.0f - 2.0f/(e + 1.0f); }
__device__ __forceinline__ u16 f2bf(float x){ __hip_bfloat16 b = __float2bfloat16(x); return *reinterpret_cast<u16*>(&b); }
__device__ __forceinline__ float bf2f(u16 u){ __hip_bfloat16 b = *reinterpret_cast<__hip_bfloat16*>(&u); return __bfloat162float(b); }

__device__ __forceinline__ float wsum(float v){
  #pragma unroll
  for (int off = 32; off > 0; off >>= 1) v += __shfl_xor(v, off, 64);
  return v;
}
__device__ __forceinline__ float wmax(float v){
  #pragma unroll
  for (int off = 32; off > 0; off >>= 1) v = fmaxf(v, __shfl_xor(v, off, 64));
  return v;
}

// ---------------- setup kernels ----------------

__global__ void k_init(const float* __restrict__ h0, const float* __restrict__ c0,
                       float* __restrict__ h_ws, float* __restrict__ c_ws, float* __restrict__ cov_ws){
  int i = blockIdx.x*256 + threadIdx.x;
  if (i < B_*H_){ h_ws[i] = h0[i]; c_ws[i] = c0[i]; }
  if (i < B_*S_){ cov_ws[i] = 0.0f; }
}

__global__ __launch_bounds__(256) void k_transpose(const float* __restrict__ in, float* __restrict__ out, int R, int C){
  __shared__ float tile[64][65];
  int c0 = blockIdx.x*64, r0 = blockIdx.y*64;
  int tid = threadIdx.x;
  int cl = tid & 63, q = tid >> 6;
  #pragma unroll
  for (int i=0;i<16;i++){
    int r = q + i*4;
    float v = 0.0f;
    if (r0 + r < R && c0 + cl < C) v = in[(size_t)(r0+r)*C + c0 + cl];
    tile[r][cl] = v;
  }
  __syncthreads();
  #pragma unroll
  for (int i=0;i<16;i++){
    int c = q + i*4;
    if (c0 + c < C && r0 + cl < R)
      out[(size_t)(c0+c)*R + r0 + cl] = tile[cl][c];
  }
}

// f32 [R][C] -> bf16 [C][R] (hi) and optional residual (lo) for split-bf16
__global__ __launch_bounds__(256) void k_convT(const float* __restrict__ in, u16* __restrict__ hi, u16* __restrict__ lo, int R, int C){
  __shared__ float tile[64][65];
  int c0 = blockIdx.x*64, r0 = blockIdx.y*64;
  int tid = threadIdx.x;
  int cl = tid & 63, q = tid >> 6;
  #pragma unroll
  for (int i=0;i<16;i++){
    int r = q + i*4;
    float v = 0.0f;
    if (r0 + r < R && c0 + cl < C) v = in[(size_t)(r0+r)*C + c0 + cl];
    tile[r][cl] = v;
  }
  __syncthreads();
  #pragma unroll
  for (int i=0;i<16;i++){
    int c = q + i*4;
    if (c0 + c < C && r0 + cl < R){
      float v = tile[cl][c];
      u16 h = f2bf(v);
      size_t o = (size_t)(c0+c)*R + r0 + cl;
      hi[o] = h;
      if (lo) lo[o] = f2bf(v - bf2f(h));
    }
  }
}

__global__ void k_conv_hilo(const float* __restrict__ in, u16* __restrict__ hi, u16* __restrict__ lo, int n4){
  int i = blockIdx.x*256 + threadIdx.x;
  if (i >= n4) return;
  float4 x = reinterpret_cast<const float4*>(in)[i];
  u16 a0 = f2bf(x.x), a1 = f2bf(x.y), a2 = f2bf(x.z), a3 = f2bf(x.w);
  uint2 hv; hv.x = (unsigned)a0 | ((unsigned)a1 << 16); hv.y = (unsigned)a2 | ((unsigned)a3 << 16);
  reinterpret_cast<uint2*>(hi)[i] = hv;
  u16 l0 = f2bf(x.x - bf2f(a0)), l1 = f2bf(x.y - bf2f(a1));
  u16 l2 = f2bf(x.z - bf2f(a2)), l3 = f2bf(x.w - bf2f(a3));
  uint2 lv; lv.x = (unsigned)l0 | ((unsigned)l1 << 16); lv.y = (unsigned)l2 | ((unsigned)l3 << 16);
  reinterpret_cast<uint2*>(lo)[i] = lv;
}

// f32 -> bf16 (no transpose), 8 elems/thread
__global__ void k_conv_bf(const float* __restrict__ in, u16* __restrict__ out, int n8){
  int i = blockIdx.x*256 + threadIdx.x;
  if (i >= n8) return;
  float4 x0 = reinterpret_cast<const float4*>(in)[2*i];
  float4 x1 = reinterpret_cast<const float4*>(in)[2*i+1];
  uint4 o;
  o.x = (unsigned)f2bf(x0.x) | ((unsigned)f2bf(x0.y) << 16);
  o.y = (unsigned)f2bf(x0.z) | ((unsigned)f2bf(x0.w) << 16);
  o.z = (unsigned)f2bf(x1.x) | ((unsigned)f2bf(x1.y) << 16);
  o.w = (unsigned)f2bf(x1.z) | ((unsigned)f2bf(x1.w) << 16);
  reinterpret_cast<uint4*>(out)[i] = o;
}

// G_ih[r][j] = b_ih[j]+b_hh[j] + sum_e emb[r][e]*W_ih[j][e]  (uses WihT[e][j])
__global__ __launch_bounds__(256) void k_gih(const float* __restrict__ emb, const float* __restrict__ WihT,
    const float* __restrict__ b_ih, const float* __restrict__ b_hh, float* __restrict__ G){
  __shared__ float em[8][128];
  int r0 = blockIdx.x*8;
  int tid = threadIdx.x;
  #pragma unroll
  for (int i=0;i<4;i++){
    int e = i*256 + tid;
    em[e>>7][e&127] = emb[(size_t)(r0 + (e>>7))*E_ + (e&127)];
  }
  __syncthreads();
  for (int jj=0;jj<8;jj++){
    int j = jj*256 + tid;
    float bias = b_ih[j] + b_hh[j];
    float acc[8];
    #pragma unroll
    for (int r=0;r<8;r++) acc[r] = bias;
    for (int e=0;e<128;e++){
      float wv = WihT[(size_t)e*H4_ + j];
      #pragma unroll
      for (int r=0;r<8;r++) acc[r] += em[r][e]*wv;
    }
    #pragma unroll
    for (int r=0;r<8;r++) G[(size_t)(r0+r)*H4_ + j] = acc[r];
  }
}

// ---------------- MFMA bf16 GEMM: C[M][N] (+= / =) A[M][K] * Bt[N][K]^T (+bias) ----------------
// optional per-(row, n-block) softmax stats (max, sum_exp) for the logits pipeline
__global__ __launch_bounds__(256, 2) void k_gemm_bf16(
    const u16* __restrict__ A, int lda, const u16* __restrict__ Bt, int ldb,
    const float* __restrict__ bias, float* __restrict__ C, int ldc,
    int M, int N, int K, int accum, float2* __restrict__ stats, int nblk)
{
  __shared__ __align__(16) u16 As[128*64];
  __shared__ __align__(16) u16 Bs[128*64];
  __shared__ float rs[128], rs2[128];
  const int tid = threadIdx.x;
  const int m0 = blockIdx.y * 128;
  const int n0 = blockIdx.x * 128;
  const int l  = tid & 63;
  const int wavebase = tid & ~63;
  const int wid = tid >> 6;
  const int wm = (wid >> 1) * 64;
  const int wn = (wid & 1) * 64;

  v4f acc[4][4];
  v4f vzero = {0.0f, 0.0f, 0.0f, 0.0f};
  #pragma unroll
  for (int i=0;i<4;i++)
    #pragma unroll
    for (int j=0;j<4;j++) acc[i][j] = vzero;

  for (int k0 = 0; k0 < K; k0 += 64){
    __syncthreads();
    #pragma unroll
    for (int jj=0;jj<4;jj++){
      int fc = jj*256 + tid;          // flat 16B-chunk id: 128 rows x 8 chunks
      int row = fc >> 3;
      int cc = (fc & 7) ^ (row & 7);  // inverse-swizzled source chunk
      const u16* g = A + (size_t)(m0 + row)*lda + k0 + cc*8;
      __builtin_amdgcn_global_load_lds(
        (__attribute__((address_space(1))) void*)g,
        (__attribute__((address_space(3))) void*)(As + (size_t)(jj*256 + wavebase)*8),
        16, 0, 0);
    }
    #pragma unroll
    for (int jj=0;jj<4;jj++){
      int fc = jj*256 + tid;
      int row = fc >> 3;
      int cc = (fc & 7) ^ (row & 7);
      int rn = n0 + row; if (rn > N-1) rn = N-1;   // clamp for N-tail (stores guarded)
      const u16* g = Bt + (size_t)rn*ldb + k0 + cc*8;
      __builtin_amdgcn_global_load_lds(
        (__attribute__((address_space(1))) void*)g,
        (__attribute__((address_space(3))) void*)(Bs + (size_t)(jj*256 + wavebase)*8),
        16, 0, 0);
    }
    __syncthreads();
    #pragma unroll
    for (int ks=0;ks<2;ks++){
      v8s af[4], bfr[4];
      #pragma unroll
      for (int rt=0;rt<4;rt++){
        int r = wm + rt*16 + (l & 15);
        int cs = (ks*4 + (l >> 4)) ^ (r & 7);
        af[rt] = *reinterpret_cast<const v8s*>(As + r*64 + cs*8);
      }
      #pragma unroll
      for (int nt=0;nt<4;nt++){
        int r = wn + nt*16 + (l & 15);
        int cs = (ks*4 + (l >> 4)) ^ (r & 7);
        bfr[nt] = *reinterpret_cast<const v8s*>(Bs + r*64 + cs*8);
      }
      #pragma unroll
      for (int rt=0;rt<4;rt++)
        #pragma unroll
        for (int nt=0;nt<4;nt++)
          acc[rt][nt] = __builtin_amdgcn_mfma_f32_16x16x32_bf16(af[rt], bfr[nt], acc[rt][nt], 0, 0, 0);
    }
  }

  const int cl = l & 15;
  const int rg = (l >> 4) * 4;
  #pragma unroll
  for (int rt=0;rt<4;rt++){
    int gr = m0 + wm + rt*16 + rg;
    #pragma unroll
    for (int nt=0;nt<4;nt++){
      int gc = n0 + wn + nt*16 + cl;
      if (gc < N){
        float* cp = C + (size_t)gr*ldc + gc;
        if (accum){
          #pragma unroll
          for (int i=0;i<4;i++) cp[(size_t)i*ldc] += acc[rt][nt][i];
        } else {
          float bv = bias ? bias[gc] : 0.0f;
          #pragma unroll
          for (int i=0;i<4;i++) cp[(size_t)i*ldc] = acc[rt][nt][i] + bv;
        }
      }
    }
  }

  if (stats){
    float tmx[4][4], tsm[4][4];
    // stage A: per-row max over this block's 128 cols
    #pragma unroll
    for (int rt=0;rt<4;rt++)
      #pragma unroll
      for (int i=0;i<4;i++){
        float mx = -1e30f;
        #pragma unroll
        for (int nt=0;nt<4;nt++){
          int gc = n0 + wn + nt*16 + cl;
          if (gc < N){
            float bv = bias ? bias[gc] : 0.0f;
            mx = fmaxf(mx, acc[rt][nt][i] + bv);
          }
        }
        #pragma unroll
        for (int off=1; off<16; off<<=1) mx = fmaxf(mx, __shfl_xor(mx, off, 64));
        tmx[rt][i] = mx;
        if (wn == 0 && cl == 0) rs[wm + rt*16 + rg + i] = mx;
      }
    __syncthreads();
    if (wn != 0){
      #pragma unroll
      for (int rt=0;rt<4;rt++)
        #pragma unroll
        for (int i=0;i<4;i++){
          float c = fmaxf(tmx[rt][i], rs[wm + rt*16 + rg + i]);
          if (cl == 0) rs[wm + rt*16 + rg + i] = c;
        }
    }
    __syncthreads();
    // stage B: per-row sum of exp(x - rowmax)
    #pragma unroll
    for (int rt=0;rt<4;rt++)
      #pragma unroll
      for (int i=0;i<4;i++){
        float rm = rs[wm + rt*16 + rg + i];
        float sm = 0.0f;
        #pragma unroll
        for (int nt=0;nt<4;nt++){
          int gc = n0 + wn + nt*16 + cl;
          if (gc < N){
            float bv = bias ? bias[gc] : 0.0f;
            sm += __expf(acc[rt][nt][i] + bv - rm);
          }
        }
        #pragma unroll
        for (int off=1; off<16; off<<=1) sm += __shfl_xor(sm, off, 64);
        tsm[rt][i] = sm;
        if (wn == 0 && cl == 0) rs2[wm + rt*16 + rg + i] = sm;
      }
    __syncthreads();
    if (wn != 0 && cl == 0){
      #pragma unroll
      for (int rt=0;rt<4;rt++)
        #pragma unroll
        for (int i=0;i<4;i++){
          int row = wm + rt*16 + rg + i;
          stats[(size_t)(m0 + row)*nblk + blockIdx.x] =
            make_float2(rs[row], tsm[rt][i] + rs2[row]);
        }
    }
  }
}

// fallback f32 GEMM for W_v when ws too small: logits = dec_states @ W_v + b_v
__global__ __launch_bounds__(256) void k_wv_f32(
  const float* __restrict__ Aah, const float* __restrict__ Wv, const float* __restrict__ bv,
  float* __restrict__ Cl)
{
  __shared__ float Asf[32][68];
  __shared__ float Bsf[32][64];
  int n0 = blockIdx.x*64, m0 = blockIdx.y*64;
  int tid = threadIdx.x;
  int tx = tid & 15, ty = tid >> 4;
  float acc[4][4] = {};
  for (int kc = 0; kc < H_; kc += 32){
    __syncthreads();
    #pragma unroll
    for (int i=0;i<8;i++){
      int e = i*256 + tid;
      Asf[e & 31][e >> 5] = Aah[(size_t)(m0 + (e >> 5))*H_ + kc + (e & 31)];
    }
    #pragma unroll
    for (int i=0;i<8;i++){
      int e = i*256 + tid;
      int nc = n0 + (e & 63); if (nc >= V_) nc = V_-1;
      Bsf[e >> 6][e & 63] = Wv[(size_t)(kc + (e >> 6))*V_ + nc];
    }
    __syncthreads();
    #pragma unroll
    for (int k=0;k<32;k++){
      float4 a4 = *reinterpret_cast<const float4*>(&Asf[k][ty*4]);
      float4 b4 = *reinterpret_cast<const float4*>(&Bsf[k][tx*4]);
      float av[4] = {a4.x, a4.y, a4.z, a4.w};
      float bv4[4] = {b4.x, b4.y, b4.z, b4.w};
      #pragma unroll
      for (int i=0;i<4;i++)
        #pragma unroll
        for (int j=0;j<4;j++)
          acc[i][j] = __builtin_fmaf(av[i], bv4[j], acc[i][j]);
    }
  }
  #pragma unroll
  for (int i=0;i<4;i++){
    int rr = m0 + ty*4 + i;
    #pragma unroll
    for (int j=0;j<4;j++){
      int cc = n0 + tx*4 + j;
      if (cc < V_) Cl[(size_t)rr*V_ + cc] = acc[i][j] + bv[cc];
    }
  }
}

// ---------------- per-step kernels ----------------

// split-K partial of gates: gp[ks][b][j] = sum_{k in ks-range} h[b][k]*W_hh[j][k]
__global__ __launch_bounds__(256) void k_gates(const float* __restrict__ h_ws, const float* __restrict__ WhhT, float* __restrict__ gp){
  __shared__ float hs[64][36];
  __shared__ float red[128][33];
  int ks = blockIdx.x;          // 0..7 (k-range 64)
  int j0 = blockIdx.y * 128;    // 0..15
  int k0 = ks * 64;
  int tid = threadIdx.x;
  #pragma unroll
  for (int i=0;i<8;i++){
    int e = i*256 + tid;
    int b = e >> 6, kl = e & 63;
    hs[kl][b] = h_ws[b*H_ + k0 + kl];
  }
  __syncthreads();
  int jl = tid & 127, kh = tid >> 7;
  int j = j0 + jl;
  float acc[32];
  #pragma unroll
  for (int b=0;b<32;b++) acc[b] = 0.0f;
  #pragma unroll 4
  for (int kk=0;kk<32;kk++){
    int k = kh*32 + kk;
    float wv = WhhT[(size_t)(k0 + k)*H4_ + j];
    #pragma unroll
    for (int bb=0;bb<8;bb++){
      float4 hv = *reinterpret_cast<const float4*>(&hs[k][bb*4]);
      acc[bb*4+0] += hv.x*wv;
      acc[bb*4+1] += hv.y*wv;
      acc[bb*4+2] += hv.z*wv;
      acc[bb*4+3] += hv.w*wv;
    }
  }
  if (kh){
    #pragma unroll
    for (int b=0;b<32;b++) red[jl][b] = acc[b];
  }
  __syncthreads();
  if (!kh){
    #pragma unroll
    for (int b=0;b<32;b++)
      gp[(size_t)(ks*32 + b)*H4_ + j] = acc[b] + red[jl][b];
  }
}

// finish LSTM pointwise (redundantly per aq) + dec partial over this block's k-range
__global__ __launch_bounds__(256) void k_dech(
  const float* __restrict__ gp, const float* __restrict__ G,
  const float* __restrict__ c_r, float* __restrict__ c_w,
  float* __restrict__ h_ws, float* __restrict__ h_all,
  const float* __restrict__ W_dec, float* __restrict__ decp, int t)
{
  __shared__ float hs[128][12];
  __shared__ float red[128][9];
  int aq = blockIdx.x, ks = blockIdx.y, bg = blockIdx.z;  // 4,4,4
  int tid = threadIdx.x;
  #pragma unroll
  for (int i=0;i<4;i++){
    int e = i*256 + tid;
    int bl = e >> 7, kl = e & 127;
    int b = bg*8 + bl;
    int hidx = ks*128 + kl;
    int r = b*T_ + t;
    const float* Gr = G + (size_t)r*H4_ + hidx;
    float gi = Gr[0], gf = Gr[512], gg = Gr[1024], go = Gr[1536];
    #pragma unroll
    for (int p=0;p<8;p++){
      const float* gpb = gp + (size_t)(p*32 + b)*H4_ + hidx;
      gi += gpb[0]; gf += gpb[512]; gg += gpb[1024]; go += gpb[1536];
    }
    float co = c_r[b*H_ + hidx];
    float cn = fsig(gf)*co + fsig(gi)*ftanh(gg);
    float hn = fsig(go)*ftanh(cn);
    hs[kl][bl] = hn;
    if (aq == 0){
      c_w[b*H_ + hidx] = cn;
      h_ws[b*H_ + hidx] = hn;
      h_all[(size_t)r*H_ + hidx] = hn;
    }
  }
  __syncthreads();
  int al = tid & 127, kh = tid >> 7;
  int a = aq*128 + al;
  float acc[8];
  #pragma unroll
  for (int i=0;i<8;i++) acc[i] = 0.0f;
  #pragma unroll 4
  for (int kk=0;kk<64;kk++){
    int k = kh*64 + kk;
    float wv = W_dec[(size_t)(ks*128 + k)*A_ + a];
    float4 hv0 = *reinterpret_cast<const float4*>(&hs[k][0]);
    float4 hv1 = *reinterpret_cast<const float4*>(&hs[k][4]);
    acc[0] += hv0.x*wv; acc[1] += hv0.y*wv; acc[2] += hv0.z*wv; acc[3] += hv0.w*wv;
    acc[4] += hv1.x*wv; acc[5] += hv1.y*wv; acc[6] += hv1.z*wv; acc[7] += hv1.w*wv;
  }
  if (kh){
    #pragma unroll
    for (int i=0;i<8;i++) red[al][i] = acc[i];
  }
  __syncthreads();
  if (!kh){
    #pragma unroll
    for (int bl=0;bl<8;bl++)
      decp[(size_t)(ks*32 + bg*8 + bl)*A_ + a] = acc[bl] + red[al][bl];
  }
}

// scores[b][s] = v . tanh(ep[b,s,:] + dec[b,:] + cov[b,s]*w_cov)   (b_att folded into ep; ep in bf16)
__global__ __launch_bounds__(256) void k_scores(
  const u16* __restrict__ ep_bf, const float* __restrict__ decp,
  const float* __restrict__ w_cov, const float* __restrict__ v_att,
  const float* __restrict__ cov_ws, const void* __restrict__ maskp,
  float* __restrict__ sc_ws)
{
  int sq = blockIdx.x, b = blockIdx.y;
  int tid = threadIdx.x;
  int w = tid >> 6, l = tid & 63;
  int a0 = l*8;
  float dec8[8], wc8[8], va8[8];
  #pragma unroll
  for (int k=0;k<8;k++){
    float d = 0.0f;
    #pragma unroll
    for (int p=0;p<4;p++) d += decp[(size_t)(p*32 + b)*A_ + a0 + k];
    dec8[k] = d;
    wc8[k] = w_cov[a0 + k];
    va8[k] = v_att[a0 + k];
  }
  const unsigned* m32 = (const unsigned*)maskp;
  const unsigned char* m8 = (const unsigned char*)maskp;
  bool bytemode = (m32[0] == 0x01010101u);
  for (int si=0; si<13; si++){
    int sl = w + si*4;
    if (sl >= 50) break;
    int s = sq*50 + sl;
    float cv = cov_ws[b*S_ + s];
    uint4 e8 = *reinterpret_cast<const uint4*>(ep_bf + (size_t)(b*S_ + s)*A_ + a0);
    unsigned uu[4] = {e8.x, e8.y, e8.z, e8.w};
    float part = 0.0f;
    #pragma unroll
    for (int j=0;j<4;j++){
      float xa = bf2f((u16)(uu[j] & 0xFFFFu)) + dec8[2*j]   + cv*wc8[2*j];
      part += va8[2*j]*ftanh(xa);
      float xb = bf2f((u16)(uu[j] >> 16))     + dec8[2*j+1] + cv*wc8[2*j+1];
      part += va8[2*j+1]*ftanh(xb);
    }
    part = wsum(part);
    if (l == 0){
      bool on = bytemode ? (m8[b*S_ + s] != 0) : (m32[b*S_ + s] != 0u);
      sc_ws[b*S_ + s] = on ? part : -1e9f;
    }
  }
}

// softmax (recomputed per block) + attn/cov outputs (dq==0) + context partial; enc in bf16
__global__ __launch_bounds__(256) void k_context(
  const float* __restrict__ sc_ws, float* __restrict__ cov_ws,
  const u16* __restrict__ enc_hi, float* __restrict__ ctxp,
  float* __restrict__ attns_out, float* __restrict__ covs_out, int t)
{
  __shared__ float att[100];
  __shared__ float cw[8];
  int dq = blockIdx.x, sh = blockIdx.y, b = blockIdx.z;   // 2,4,32
  int tid = threadIdx.x;
  int w = tid >> 6;
  float v1 = sc_ws[b*S_ + tid];
  float v2 = (tid + 256 < S_) ? sc_ws[b*S_ + tid + 256] : -1e30f;
  float mx = wmax(fmaxf(v1, v2));
  if ((tid & 63) == 0) cw[w] = mx;
  __syncthreads();
  float m4 = fmaxf(fmaxf(cw[0], cw[1]), fmaxf(cw[2], cw[3]));
  float e1 = __expf(v1 - m4) + ((tid + 256 < S_) ? __expf(v2 - m4) : 0.0f);
  float sm = wsum(e1);
  if ((tid & 63) == 0) cw[4 + w] = sm;
  __syncthreads();
  float invZ = 1.0f/(cw[4] + cw[5] + cw[6] + cw[7]);
  int r = b*T_ + t;
  if (tid < 100){
    int s = sh*100 + tid;
    float aval = __expf(sc_ws[b*S_ + s] - m4)*invZ;
    att[tid] = aval;
    if (dq == 0){
      attns_out[(size_t)r*S_ + s] = aval;
      float cn = cov_ws[b*S_ + s] + aval;
      covs_out[(size_t)r*S_ + s] = cn;
      cov_ws[b*S_ + s] = cn;
    }
  }
  __syncthreads();
  int d0 = dq*512 + tid*2;
  const u16* encb = enc_hi + (size_t)(b*S_ + sh*100)*H2_ + d0;
  float a0v = 0.0f, a1v = 0.0f;
  #pragma unroll 4
  for (int si=0; si<100; si++){
    unsigned uv = *reinterpret_cast<const unsigned*>(encb + (size_t)si*H2_);
    float av = att[si];
    a0v += av*bf2f((u16)(uv & 0xFFFFu));
    a1v += av*bf2f((u16)(uv >> 16));
  }
  *reinterpret_cast<float2*>(ctxp + (size_t)(sh*R_ + r)*H2_ + d0) = make_float2(a0v, a1v);
}

// ---------------- post-loop kernels ----------------

__global__ void k_catsum(const float* __restrict__ ctxp, const float* __restrict__ h_all, float* __restrict__ catbuf){
  int r = blockIdx.y;
  int d = blockIdx.x*256 + threadIdx.x;
  float v;
  if (d < H2_){
    v = ctxp[(size_t)(0*R_ + r)*H2_ + d] + ctxp[(size_t)(1*R_ + r)*H2_ + d]
      + ctxp[(size_t)(2*R_ + r)*H2_ + d] + ctxp[(size_t)(3*R_ + r)*H2_ + d];
  } else {
    v = h_all[(size_t)r*H_ + (d - H2_)];
  }
  catbuf[(size_t)r*H3_ + d] = v;
}

// fp32 tiled GEMM: dec_states = tanh(catbuf @ W_ah + b_ah); optional bf16 copy
__global__ __launch_bounds__(256) void k_ahgemm(
  const float* __restrict__ Acat, const float* __restrict__ W_ah, const float* __restrict__ b_ah,
  float* __restrict__ dec_states, u16* __restrict__ ah_bf)
{
  __shared__ float Asf[32][68];
  __shared__ float Bsf[32][64];
  int n0 = blockIdx.x*64, m0 = blockIdx.y*64;
  int tid = threadIdx.x;
  int tx = tid & 15, ty = tid >> 4;
  float acc[4][4] = {};
  for (int kc = 0; kc < H3_; kc += 32){
    __syncthreads();
    #pragma unroll
    for (int i=0;i<8;i++){
      int e = i*256 + tid;
      Asf[e & 31][e >> 5] = Acat[(size_t)(m0 + (e >> 5))*H3_ + kc + (e & 31)];
    }
    #pragma unroll
    for (int i=0;i<8;i++){
      int e = i*256 + tid;
      Bsf[e >> 6][e & 63] = W_ah[(size_t)(kc + (e >> 6))*H_ + n0 + (e & 63)];
    }
    __syncthreads();
    #pragma unroll
    for (int k=0;k<32;k++){
      float4 a4 = *reinterpret_cast<const float4*>(&Asf[k][ty*4]);
      float4 b4 = *reinterpret_cast<const float4*>(&Bsf[k][tx*4]);
      float av[4] = {a4.x, a4.y, a4.z, a4.w};
      float bv[4] = {b4.x, b4.y, b4.z, b4.w};
      #pragma unroll
      for (int i=0;i<4;i++)
        #pragma unroll
        for (int j=0;j<4;j++)
          acc[i][j] = __builtin_fmaf(av[i], bv[j], acc[i][j]);
    }
  }
  #pragma unroll
  for (int i=0;i<4;i++){
    int rr = m0 + ty*4 + i;
    #pragma unroll
    for (int j=0;j<4;j++){
      int cc = n0 + tx*4 + j;
      float v = ftanh(acc[i][j] + b_ah[cc]);
      dec_states[(size_t)rr*H_ + cc] = v;
      if (ah_bf) ah_bf[(size_t)rr*H_ + cc] = f2bf(v);
    }
  }
}

__global__ __launch_bounds__(512) void k_pgen(const float* __restrict__ catbuf, const float* __restrict__ emb,
  const float* __restrict__ W_pg, const float* __restrict__ b_pg, float* __restrict__ pgens)
{
  int w = threadIdx.x >> 6, l = threadIdx.x & 63;
  int r = blockIdx.x*8 + w;
  float part = 0.0f;
  for (int d = l; d < PGK_; d += 64){
    float x = (d < H3_) ? catbuf[(size_t)r*H3_ + d] : emb[(size_t)r*E_ + (d - H3_)];
    part += x*W_pg[d];
  }
  part = wsum(part);
  if (l == 0) pgens[r] = fsig(part + b_pg[0]);
}

// per-row final: stats-merge (or in-kernel max/Z) -> bitmask+hash scatter -> fast log transform
__global__ __launch_bounds__(512) void k_final2(
  float* __restrict__ logits, const float* __restrict__ pgens,
  const float* __restrict__ attns, const int* __restrict__ src,
  const float2* __restrict__ stats, int nblk)
{
  __shared__ unsigned bits[1568];
  __shared__ unsigned keys[1024];
  __shared__ float vals[1024];
  __shared__ float sred[18];
  int r = blockIdx.x;
  int b = r >> 5;
  int tid = threadIdx.x;
  int w = tid >> 6, l = tid & 63;
  float* row = logits + (size_t)r*V_;

  for (int i = tid; i < 1568; i += 512) bits[i] = 0u;
  for (int i = tid; i < 1024; i += 512){ keys[i] = 0xFFFFFFFFu; vals[i] = 0.0f; }

  if (stats){
    float m = -1e30f, Z = 0.0f;
    if (tid < nblk){ float2 st = stats[(size_t)r*nblk + tid]; m = st.x; Z = st.y; }
    #pragma unroll
    for (int off=32; off>0; off>>=1){
      float mo = __shfl_xor(m, off, 64);
      float Zo = __shfl_xor(Z, off, 64);
      float nm = fmaxf(m, mo);
      Z = Z*__expf(m - nm) + Zo*__expf(mo - nm);
      m = nm;
    }
    if (l == 0){ sred[w*2] = m; sred[w*2+1] = Z; }
    __syncthreads();
    if (tid == 0){
      float gm = -1e30f, gz = 0.0f;
      #pragma unroll
      for (int i=0;i<8;i++){
        float mi = sred[i*2], zi = sred[i*2+1];
        float nm = fmaxf(gm, mi);
        gz = gz*__expf(gm - nm) + zi*__expf(mi - nm);
        gm = nm;
      }
      sred[16] = gm; sred[17] = gz;
    }
    __syncthreads();
  } else {
    // pass A: max
    float m = -1e30f;
    for (int j = tid; j < V_/4; j += 512){
      float4 x = reinterpret_cast<const float4*>(row)[j];
      m = fmaxf(fmaxf(m, x.x), fmaxf(fmaxf(x.y, x.z), x.w));
    }
    m = wmax(m);
    if (l == 0) sred[w] = m;
    __syncthreads();
    if (tid == 0){
      float gm = -1e30f;
      #pragma unroll
      for (int i=0;i<8;i++) gm = fmaxf(gm, sred[i]);
      sred[16] = gm;
    }
    __syncthreads();
    float gm = sred[16];
    float z = 0.0f;
    for (int j = tid; j < V_/4; j += 512){
      float4 x = reinterpret_cast<const float4*>(row)[j];
      z += __expf(x.x-gm) + __expf(x.y-gm) + __expf(x.z-gm) + __expf(x.w-gm);
    }
    z = wsum(z);
    if (l == 0) sred[8 + w] = z;
    __syncthreads();
    if (tid == 0){
      float gz = 0.0f;
      #pragma unroll
      for (int i=0;i<8;i++) gz += sred[8 + i];
      sred[17] = gz;
    }
    __syncthreads();
  }

  float gm = sred[16];
  float gZ = sred[17];
  float pg = pgens[r];
  float scale = pg / gZ;
  float lscale = __logf(scale);

  if (tid < S_){
    int tok = src[b*S_ + tid];
    float add = (1.0f - pg)*attns[(size_t)r*S_ + tid];
    atomicOr(&bits[tok >> 5], 1u << (tok & 31));
    unsigned h = ((unsigned)tok * 2654435761u) >> 22;
    while (true){
      unsigned prev = atomicCAS(&keys[h], 0xFFFFFFFFu, (unsigned)tok);
      if (prev == 0xFFFFFFFFu || prev == (unsigned)tok){
        atomicAdd(&vals[h], add);
        break;
      }
      h = (h + 1) & 1023;
    }
  }
  __syncthreads();

  for (int j = tid; j < V_/4; j += 512){
    float4 x = reinterpret_cast<const float4*>(row)[j];
    int v = 4*j;
    float o[4];
    float xv[4] = {x.x, x.y, x.z, x.w};
    #pragma unroll
    for (int k=0;k<4;k++){
      int vv = v + k;
      bool hit = (bits[vv >> 5] >> (vv & 31)) & 1u;
      float t = xv[k] - gm + lscale;
      if (!hit && t > -25.0f){
        o[k] = t;
      } else {
        float p = __expf(xv[k] - gm)*scale;
        if (hit){
          unsigned h = ((unsigned)vv * 2654435761u) >> 22;
          while (keys[h] != 0xFFFFFFFFu){
            if (keys[h] == (unsigned)vv){ p += vals[h]; break; }
            h = (h + 1) & 1023;
          }
        }
        o[k] = __logf(p + 1e-20f);
      }
    }
    reinterpret_cast<float4*>(row)[j] = make_float4(o[0], o[1], o[2], o[3]);
  }
}

// ---------------- host ----------------

extern "C" void kernel_launch(void* const* d_in, const int* in_sizes, int n_in,
                              void* d_out, int out_size, void* d_ws, size_t ws_size,
                              hipStream_t stream)
{
  const int* src_tokens = (const int*)d_in[0];
  const float* embedded = (const float*)d_in[1];
  const float* enc      = (const float*)d_in[2];
  const void*  maskp    = (const void*)d_in[3];
  const float* h0  = (const float*)d_in[4];
  const float* c0  = (const float*)d_in[5];
  const float* W_ih = (const float*)d_in[6];
  const float* W_hh = (const float*)d_in[7];
  const float* b_ih = (const float*)d_in[8];
  const float* b_hh = (const float*)d_in[9];
  const float* W_enc = (const float*)d_in[10];
  const float* W_dec = (const float*)d_in[11];
  const float* w_cov = (const float*)d_in[12];
  const float* b_att = (const float*)d_in[13];
  const float* v_att = (const float*)d_in[14];
  const float* W_ah  = (const float*)d_in[15];
  const float* b_ah  = (const float*)d_in[16];
  const float* W_pg  = (const float*)d_in[17];
  const float* b_pg  = (const float*)d_in[18];
  const float* W_v   = (const float*)d_in[19];
  const float* b_v   = (const float*)d_in[20];
  (void)in_sizes; (void)n_in; (void)out_size;

  float* outp = (float*)d_out;
  float* logps = outp;                                  // (B,T,V)   204.8 MB
  float* dec_states = logps + (size_t)R_*V_;            // (B,T,H)
  float* attns = dec_states + (size_t)R_*H_;            // (B,T,S)
  float* covs  = attns + (size_t)R_*S_;                 // (B,T,S)
  float* pgens = covs + (size_t)R_*S_;                  // (B,T)

  // ---- big transients live INSIDE the logps output region (dead until W_v GEMM) ----
  char* sp = (char*)logps;
  auto salloc = [&](size_t bytes) -> void* {
    void* p = (void*)sp;
    sp += (bytes + 255) & ~(size_t)255;
    return p;
  };
  float* ep     = (float*)salloc((size_t)B_*S_*A_*4);    // enc_proj + b_att (fp32 accum)
  u16* ep_bf    = (u16*)salloc((size_t)B_*S_*A_*2);      // bf16 copy for k_scores
  u16* enc_hi   = (u16*)salloc((size_t)B_*S_*H2_*2);
  u16* enc_lo   = (u16*)salloc((size_t)B_*S_*H2_*2);
  u16* WencT_hi = (u16*)salloc((size_t)A_*H2_*2);
  u16* WencT_lo = (u16*)salloc((size_t)A_*H2_*2);
  float* WihT   = (float*)salloc((size_t)E_*H4_*4);
  float* WhhT   = (float*)salloc((size_t)H_*H4_*4);
  float* Gih    = (float*)salloc((size_t)R_*H4_*4);      // emb@W_ih^T + biases
  float* ctxp   = (float*)salloc((size_t)4*R_*H2_*4);    // context s-partials
  float* catbuf = (float*)salloc((size_t)R_*H3_*4);      // [context | h]
  float* h_all  = (float*)salloc((size_t)R_*H_*4);
  float* gp     = (float*)salloc((size_t)8*B_*H4_*4);    // gate k-partials
  float* decp   = (float*)salloc((size_t)4*B_*A_*4);     // dec k-partials
  float* sc_ws  = (float*)salloc((size_t)B_*S_*4);
  float* cov_ws = (float*)salloc((size_t)B_*S_*4);
  float* h_ws   = (float*)salloc((size_t)B_*H_*4);
  float* c_ws0  = (float*)salloc((size_t)B_*H_*4);
  float* c_ws1  = (float*)salloc((size_t)B_*H_*4);
  // total ~161 MB < 204.8 MB of logps -- all consumed before W_v GEMM writes logps

  // ---- d_ws: only buffers live WHILE logps is being written ----
  char* wp = (char*)d_ws;
  auto walloc = [&](size_t bytes) -> void* {
    void* p = (void*)wp;
    wp += (bytes + 255) & ~(size_t)255;
    return p;
  };
  u16* ah_bf = (u16*)walloc((size_t)R_*H_*2);            // 1.05 MB
  u16* WvT   = (u16*)walloc((size_t)V_*H_*2);            // 51.2 MB
  float2* stats = (float2*)walloc((size_t)R_*NBLKV_*8);  // 3.2 MB
  const size_t ws_fast  = (size_t)R_*H_*2 + (size_t)V_*H_*2 + 512;
  const size_t ws_stats = ws_fast + (size_t)R_*NBLKV_*8 + 256;
  const bool fast_wv   = (ws_size >= ws_fast);
  const bool use_stats = (ws_size >= ws_stats);

  // setup
  k_init<<<64, 256, 0, stream>>>(h0, c0, h_ws, c_ws0, cov_ws);
  k_transpose<<<dim3(8,32), 256, 0, stream>>>(W_hh, WhhT, H4_, H_);
  k_transpose<<<dim3(2,32), 256, 0, stream>>>(W_ih, WihT, H4_, E_);
  k_gih<<<128, 256, 0, stream>>>(embedded, WihT, b_ih, b_hh, Gih);
  k_conv_hilo<<<(B_*S_*H2_/4 + 255)/256, 256, 0, stream>>>(enc, enc_hi, enc_lo, B_*S_*H2_/4);
  k_convT<<<dim3(8,16), 256, 0, stream>>>(W_enc, WencT_hi, WencT_lo, H2_, A_);
  if (fast_wv)
    k_convT<<<dim3((V_+63)/64, 8), 256, 0, stream>>>(W_v, WvT, (u16*)nullptr, H_, V_);

  // enc_proj (split-bf16, 3 passes: Ah*Bh + Ah*Bl + Al*Bh), bias=b_att on pass 1
  dim3 gep(A_/128, (B_*S_)/128);
  k_gemm_bf16<<<gep, 256, 0, stream>>>(enc_hi, H2_, WencT_hi, H2_, b_att, ep, A_, B_*S_, A_, H2_, 0, nullptr, 0);
  k_gemm_bf16<<<gep, 256, 0, stream>>>(enc_hi, H2_, WencT_lo, H2_, nullptr, ep, A_, B_*S_, A_, H2_, 1, nullptr, 0);
  k_gemm_bf16<<<gep, 256, 0, stream>>>(enc_lo, H2_, WencT_hi, H2_, nullptr, ep, A_, B_*S_, A_, H2_, 1, nullptr, 0);
  k_conv_bf<<<(B_*S_*A_/8 + 255)/256, 256, 0, stream>>>(ep, ep_bf, B_*S_*A_/8);

  // recurrence
  for (int t = 0; t < T_; ++t){
    float* c_r = (t & 1) ? c_ws1 : c_ws0;
    float* c_w = (t & 1) ? c_ws0 : c_ws1;
    k_gates<<<dim3(8,16), 256, 0, stream>>>(h_ws, WhhT, gp);
    k_dech<<<dim3(4,4,4), 256, 0, stream>>>(gp, Gih, c_r, c_w, h_ws, h_all, W_dec, decp, t);
    k_scores<<<dim3(8,32), 256, 0, stream>>>(ep_bf, decp, w_cov, v_att, cov_ws, maskp, sc_ws);
    k_context<<<dim3(2,4,32), 256, 0, stream>>>(sc_ws, cov_ws, enc_hi, ctxp, attns, covs, t);
  }

  // batched tail
  k_catsum<<<dim3(6, R_), 256, 0, stream>>>(ctxp, h_all, catbuf);
  k_ahgemm<<<dim3(8,16), 256, 0, stream>>>(catbuf, W_ah, b_ah, dec_states, fast_wv ? ah_bf : (u16*)nullptr);
  k_pgen<<<128, 512, 0, stream>>>(catbuf, embedded, W_pg, b_pg, pgens);

  // logits: overwrites the whole logps region (including all scratch above)
  if (fast_wv)
    k_gemm_bf16<<<dim3(NBLKV_, R_/128), 256, 0, stream>>>(ah_bf, H_, WvT, H_, b_v, logps, V_, R_, V_, H_, 0,
                                                          use_stats ? stats : nullptr, NBLKV_);
  else
    k_wv_f32<<<dim3((V_+63)/64, R_/64), 256, 0, stream>>>(dec_states, W_v, b_v, logps);

  k_final2<<<R_, 512, 0, stream>>>(logps, pgens, attns, src_tokens,
                                   (fast_wv && use_stats) ? stats : nullptr, NBLKV_);
}